// Round 2
// baseline (8028.832 us; speedup 1.0000x reference)
//
#include <hip/hip_runtime.h>
#include <hip/hip_bf16.h>
#include <math.h>

// Problem constants
#define N_TRAIN 4096
#define N_FEAT  64
#define NHID    256
#define ENC     256
#define GH      256
#define AH      64
#define NANTES  32768
#define TSTEPS  32

__device__ __forceinline__ float sigmoidf_(float x) {
    return 1.0f / (1.0f + __expf(-x));
}
__device__ __forceinline__ float tanhf_(float x) {
    // tanh(x) = 1 - 2/(e^{2x}+1); exact at +-inf, ~1e-7 rel error
    return 1.0f - 2.0f / (__expf(2.0f * x) + 1.0f);
}

// ---------------------------------------------------------------------------
// Kernel 0: zero the e-sum accumulator (32 x 256 floats)
// ---------------------------------------------------------------------------
__global__ void zero_kernel(float* __restrict__ esum) {
    int tid = blockIdx.x * blockDim.x + threadIdx.x;
    for (int i = tid; i < TSTEPS * GH; i += gridDim.x * blockDim.x)
        esum[i] = 0.0f;
}

// ---------------------------------------------------------------------------
// Kernel A: fused encoder -> x_proj -> 32-step LSTM -> per-step h column sums
// Grid: 256 blocks x 512 threads. Block b owns rows [b*16, b*16+16).
// Thread (j = tid&255, rh = tid>>8) owns hidden column j for 8 rows.
// K-loop is hand-pipelined: 16-wide chunks, ping-pong register weight
// buffers so ~16 dwordx4 loads are in flight under 512 FMAs.
// ---------------------------------------------------------------------------
__global__ __launch_bounds__(512, 2) void lstm_kernel(
    const float* __restrict__ ctx,
    const float* __restrict__ encW1, const float* __restrict__ encb1,
    const float* __restrict__ encW2, const float* __restrict__ encb2,
    const float* __restrict__ Wih,  const float* __restrict__ Whh,
    const float* __restrict__ bih,  const float* __restrict__ bhh,
    float* __restrict__ esum)
{
    __shared__ float ctx_lds[16 * N_FEAT];   // 4 KB
    __shared__ float bufA[16 * 256];         // 16 KB
    __shared__ float bufB[16 * 256];         // 16 KB

    const int tid   = threadIdx.x;
    const int j     = tid & 255;
    const int rh    = tid >> 8;       // 0 or 1
    const int rbase = rh * 8;
    const int r0    = blockIdx.x * 16;

    // ---- stage context rows ----
    for (int t = tid; t < 16 * N_FEAT; t += 512)
        ctx_lds[t] = ctx[r0 * N_FEAT + t];
    __syncthreads();

    // ---- hid = relu(ctx @ encW1 + b1) ----
    {
        float acc[8];
        float b = encb1[j];
        #pragma unroll
        for (int r = 0; r < 8; ++r) acc[r] = b;
        for (int k = 0; k < N_FEAT; ++k) {
            float w = encW1[k * NHID + j];
            #pragma unroll
            for (int r = 0; r < 8; ++r)
                acc[r] = fmaf(ctx_lds[(rbase + r) * N_FEAT + k], w, acc[r]);
        }
        #pragma unroll
        for (int r = 0; r < 8; ++r)
            bufA[(rbase + r) * 256 + j] = fmaxf(acc[r], 0.0f);
    }
    __syncthreads();

    // ---- phi = hid @ encW2 + b2 ----
    {
        float p[8];
        float b = encb2[j];
        #pragma unroll
        for (int r = 0; r < 8; ++r) p[r] = b;
        for (int k = 0; k < NHID; ++k) {
            float w = encW2[k * ENC + j];
            #pragma unroll
            for (int r = 0; r < 8; ++r)
                p[r] = fmaf(bufA[(rbase + r) * 256 + k], w, p[r]);
        }
        __syncthreads();   // all reads of hid done
        #pragma unroll
        for (int r = 0; r < 8; ++r)
            bufA[(rbase + r) * 256 + j] = p[r];
    }
    __syncthreads();

    // ---- x_proj[g][r] for gate column m = g*256 + j ----
    float xp[4][8];
    #pragma unroll
    for (int g = 0; g < 4; ++g) {
        int m = g * 256 + j;
        float b = bih[m] + bhh[m];
        #pragma unroll
        for (int r = 0; r < 8; ++r) xp[g][r] = b;
        const float4* wrow = (const float4*)(Wih + m * ENC);
        for (int k4 = 0; k4 < ENC / 4; ++k4) {
            float4 w = wrow[k4];
            #pragma unroll
            for (int r = 0; r < 8; ++r) {
                const float* ph = &bufA[(rbase + r) * 256 + k4 * 4];
                float v = xp[g][r];
                v = fmaf(ph[0], w.x, v);
                v = fmaf(ph[1], w.y, v);
                v = fmaf(ph[2], w.z, v);
                v = fmaf(ph[3], w.w, v);
                xp[g][r] = v;
            }
        }
    }
    __syncthreads();   // done reading bufA (phi) before step 0 overwrites it

    // ---- LSTM over 32 steps ----
    float h[8], c[8];
    #pragma unroll
    for (int r = 0; r < 8; ++r) { h[r] = 0.0f; c[r] = 0.0f; }

    const float4* wbase0 = (const float4*)(Whh + (0 * 256 + j) * 256);
    const float4* wbase1 = (const float4*)(Whh + (1 * 256 + j) * 256);
    const float4* wbase2 = (const float4*)(Whh + (2 * 256 + j) * 256);
    const float4* wbase3 = (const float4*)(Whh + (3 * 256 + j) * 256);

#define LOADW(dst, c_) do {                                                  \
        _Pragma("unroll") for (int q = 0; q < 4; ++q) {                      \
            dst[0][q] = wbase0[(c_) * 4 + q];                                \
            dst[1][q] = wbase1[(c_) * 4 + q];                                \
            dst[2][q] = wbase2[(c_) * 4 + q];                                \
            dst[3][q] = wbase3[(c_) * 4 + q];                                \
        }                                                                    \
    } while (0)

#define COMPW(w_, c_) do {                                                   \
        _Pragma("unroll") for (int r = 0; r < 8; ++r) {                      \
            const float* hp = &hb[(rbase + r) * 256 + (c_) * 16];            \
            _Pragma("unroll") for (int q = 0; q < 4; ++q) {                  \
                float4 hv = *(const float4*)(hp + q * 4);                    \
                _Pragma("unroll") for (int g = 0; g < 4; ++g) {              \
                    float a = acc[g][r];                                     \
                    a = fmaf(hv.x, w_[g][q].x, a);                           \
                    a = fmaf(hv.y, w_[g][q].y, a);                           \
                    a = fmaf(hv.z, w_[g][q].z, a);                           \
                    a = fmaf(hv.w, w_[g][q].w, a);                           \
                    acc[g][r] = a;                                           \
                }                                                            \
            }                                                                \
        }                                                                    \
    } while (0)

    for (int t = 0; t < TSTEPS; ++t) {
        float* hb = (t & 1) ? bufB : bufA;
        // publish h into LDS (double-buffered -> one barrier per step)
        #pragma unroll
        for (int r = 0; r < 8; ++r)
            hb[(rbase + r) * 256 + j] = h[r];
        __syncthreads();

        float acc[4][8];
        #pragma unroll
        for (int g = 0; g < 4; ++g)
            #pragma unroll
            for (int r = 0; r < 8; ++r) acc[g][r] = xp[g][r];

        float4 wA[4][4], wB[4][4];
        LOADW(wA, 0);
        #pragma unroll 1
        for (int c2 = 0; c2 < 8; ++c2) {
            const int c = 2 * c2;
            LOADW(wB, c + 1);           // prefetch odd chunk
            COMPW(wA, c);               // compute even chunk
            if (c2 < 7) LOADW(wA, c + 2);  // prefetch next even chunk
            COMPW(wB, c + 1);           // compute odd chunk
        }

        float hs = 0.0f;
        #pragma unroll
        for (int r = 0; r < 8; ++r) {
            float iv = sigmoidf_(acc[0][r]);
            float fv = sigmoidf_(acc[1][r]);
            float gv = tanhf_(acc[2][r]);
            float ov = sigmoidf_(acc[3][r]);
            c[r] = fv * c[r] + iv * gv;
            h[r] = ov * tanhf_(c[r]);
            hs += h[r];
        }
        atomicAdd(&esum[t * GH + j], hs);
        // no trailing barrier: next step writes the other LDS buffer
    }
#undef LOADW
#undef COMPW
}

// ---------------------------------------------------------------------------
// Kernel C: proj[t][c] = (esum[t]/4096) @ W1_h + att_b1[c]
// Grid: 32 blocks x 256 threads; K split 4 ways, LDS reduce.
// ---------------------------------------------------------------------------
__global__ void proj_kernel(const float* __restrict__ esum,
                            const float* __restrict__ attW1,
                            const float* __restrict__ attb1,
                            float* __restrict__ proj)
{
    __shared__ float part[4][AH];
    const int t   = blockIdx.x;
    const int cix = threadIdx.x & 63;
    const int g   = threadIdx.x >> 6;      // 0..3 -> k range
    float a = 0.0f;
    #pragma unroll 4
    for (int k = g * 64; k < g * 64 + 64; ++k) {
        float e = esum[t * GH + k] * (1.0f / (float)N_TRAIN);
        a = fmaf(e, attW1[(size_t)(N_TRAIN + k) * AH + cix], a);
    }
    part[g][cix] = a;
    __syncthreads();
    if (threadIdx.x < AH)
        proj[t * AH + cix] = part[0][cix] + part[1][cix] + part[2][cix] +
                             part[3][cix] + attb1[cix];
}

// ---------------------------------------------------------------------------
// Kernel D: S_proj (registers) fused with per-step scores.
// Grid: 512 blocks x 256 threads. Block owns 64 antes; thread (a = tid&63,
// ch = tid>>6) accumulates cols [ch*16, ch*16+16).
// S reads hand-pipelined: 16-row register ping-pong prefetch.
// ---------------------------------------------------------------------------
__global__ __launch_bounds__(256, 2) void scores_kernel(
    const float* __restrict__ S,
    const float* __restrict__ attW1,
    const float* __restrict__ proj,
    const float* __restrict__ attw2,
    const float* __restrict__ attb2,
    float* __restrict__ out)
{
    __shared__ float wl[64 * AH];        // 16 KB: 64-row chunk of att_W1
    __shared__ float projl[TSTEPS * AH]; // 8 KB
    __shared__ float w2l[AH];
    __shared__ float part[256];

    const int tid = threadIdx.x;
    const int a0  = blockIdx.x * 64;
    const int ai  = tid & 63;
    const int ch  = tid >> 6;            // 0..3, cols ch*16..+16
    const int a   = a0 + ai;

    float sp[16];
    #pragma unroll
    for (int q = 0; q < 16; ++q) sp[q] = 0.0f;

#define LOADS(dst, base_row) do {                                            \
        _Pragma("unroll") for (int i = 0; i < 16; ++i)                       \
            dst[i] = Scol[(size_t)((base_row) + i) * NANTES];                \
    } while (0)

#define COMPS(src, base_row) do {                                            \
        _Pragma("unroll") for (int i = 0; i < 16; ++i) {                     \
            const float* w = &wl[((base_row) + i) * AH + ch * 16];           \
            float s = src[i];                                                \
            _Pragma("unroll") for (int q = 0; q < 16; ++q)                   \
                sp[q] = fmaf(s, w[q], sp[q]);                                \
        }                                                                    \
    } while (0)

    for (int chunk = 0; chunk < N_TRAIN / 64; ++chunk) {
        __syncthreads();
        {   // stage 64x64 chunk of att_W1 (16 KB, contiguous) as float4
            const float4* src = (const float4*)(attW1 + (size_t)chunk * 64 * AH);
            float4* dstv = (float4*)wl;
            for (int i = tid; i < 64 * AH / 4; i += 256) dstv[i] = src[i];
        }
        __syncthreads();

        const float* Scol = S + (size_t)(chunk * 64) * NANTES + a;
        float sA[16], sB[16];
        LOADS(sA, 0);
        LOADS(sB, 16);
        COMPS(sA, 0);
        LOADS(sA, 32);
        COMPS(sB, 16);
        LOADS(sB, 48);
        COMPS(sA, 32);
        COMPS(sB, 48);
    }
#undef LOADS
#undef COMPS

    for (int t = tid; t < TSTEPS * AH; t += 256) projl[t] = proj[t];
    if (tid < AH) w2l[tid] = attw2[tid];
    __syncthreads();

    const float b2v = attb2[0];
    for (int t = 0; t < TSTEPS; ++t) {
        float s = 0.0f;
        const float* pr  = &projl[t * AH + ch * 16];
        const float* w2p = &w2l[ch * 16];
        #pragma unroll
        for (int q = 0; q < 16; ++q)
            s += fmaxf(sp[q] + pr[q], 0.0f) * w2p[q];
        part[tid] = s;
        __syncthreads();
        if (tid < 64)
            out[(size_t)t * NANTES + a0 + tid] =
                part[tid] + part[tid + 64] + part[tid + 128] + part[tid + 192] + b2v;
        __syncthreads();
    }
}

// ---------------------------------------------------------------------------
// Kernel E: per-step argmax over 32768 antes (first-max semantics).
// ---------------------------------------------------------------------------
__global__ void argmax_kernel(const float* __restrict__ scores,
                              float* __restrict__ out)
{
    __shared__ float bv[256];
    __shared__ int   bidx[256];
    const int t = blockIdx.x, tid = threadIdx.x;
    float best = -INFINITY;
    int   bi   = 0x7fffffff;
    for (int a = tid; a < NANTES; a += 256) {
        float v = scores[(size_t)t * NANTES + a];
        if (v > best) { best = v; bi = a; }
    }
    bv[tid] = best; bidx[tid] = bi;
    __syncthreads();
    for (int s = 128; s > 0; s >>= 1) {
        if (tid < s) {
            if (bv[tid + s] > bv[tid] ||
                (bv[tid + s] == bv[tid] && bidx[tid + s] < bidx[tid])) {
                bv[tid] = bv[tid + s];
                bidx[tid] = bidx[tid + s];
            }
        }
        __syncthreads();
    }
    if (tid == 0)
        out[(size_t)TSTEPS * NANTES + t] = (float)bidx[0];
}

// ---------------------------------------------------------------------------
extern "C" void kernel_launch(void* const* d_in, const int* in_sizes, int n_in,
                              void* d_out, int out_size, void* d_ws, size_t ws_size,
                              hipStream_t stream)
{
    const float* ctx   = (const float*)d_in[0];
    const float* S     = (const float*)d_in[1];
    const float* encW1 = (const float*)d_in[2];
    const float* encb1 = (const float*)d_in[3];
    const float* encW2 = (const float*)d_in[4];
    const float* encb2 = (const float*)d_in[5];
    const float* Wih   = (const float*)d_in[6];
    const float* Whh   = (const float*)d_in[7];
    const float* bih   = (const float*)d_in[8];
    const float* bhh   = (const float*)d_in[9];
    const float* attW1 = (const float*)d_in[10];
    const float* attb1 = (const float*)d_in[11];
    const float* attw2 = (const float*)d_in[12];
    const float* attb2 = (const float*)d_in[13];

    float* esum = (float*)d_ws;                  // 32*256 floats
    float* proj = esum + TSTEPS * GH;            // 32*64 floats
    float* out  = (float*)d_out;

    zero_kernel<<<dim3(8), dim3(256), 0, stream>>>(esum);
    lstm_kernel<<<dim3(N_TRAIN / 16), dim3(512), 0, stream>>>(
        ctx, encW1, encb1, encW2, encb2, Wih, Whh, bih, bhh, esum);
    proj_kernel<<<dim3(TSTEPS), dim3(256), 0, stream>>>(esum, attW1, attb1, proj);
    scores_kernel<<<dim3(NANTES / 64), dim3(256), 0, stream>>>(
        S, attW1, proj, attw2, attb2, out);
    argmax_kernel<<<dim3(TSTEPS), dim3(256), 0, stream>>>(out, out);
}

// Round 3
// 2934.117 us; speedup vs baseline: 2.7364x; 2.7364x over previous
//
#include <hip/hip_runtime.h>
#include <hip/hip_bf16.h>
#include <math.h>

// Problem constants
#define N_TRAIN 4096
#define N_FEAT  64
#define NHID    256
#define ENC     256
#define GH      256
#define AH      64
#define NANTES  32768
#define TSTEPS  32

__device__ __forceinline__ float sigmoidf_(float x) {
    return 1.0f / (1.0f + __expf(-x));
}
__device__ __forceinline__ float tanhf_(float x) {
    // tanh(x) = 1 - 2/(e^{2x}+1); exact at +-inf, ~1e-7 rel error
    return 1.0f - 2.0f / (__expf(2.0f * x) + 1.0f);
}

// ---------------------------------------------------------------------------
// Kernel 0: zero the e-sum accumulator (32 x 256 floats)
// ---------------------------------------------------------------------------
__global__ void zero_kernel(float* __restrict__ esum) {
    int tid = blockIdx.x * blockDim.x + threadIdx.x;
    for (int i = tid; i < TSTEPS * GH; i += gridDim.x * blockDim.x)
        esum[i] = 0.0f;
}

// ---------------------------------------------------------------------------
// Kernel A: fused encoder -> x_proj -> 32-step LSTM -> per-step h column sums
// Grid: 256 blocks x 512 threads. Block b owns rows [b*16, b*16+16).
// Thread (j = tid&255, rh = tid>>8) owns hidden column j for 8 rows.
// K-loop hand-pipelined with 8-wide ping-pong register chunks.
// __launch_bounds__(512,1): 256-VGPR budget -> no spill (~175 regs needed).
// ---------------------------------------------------------------------------
__global__ __launch_bounds__(512, 1) void lstm_kernel(
    const float* __restrict__ ctx,
    const float* __restrict__ encW1, const float* __restrict__ encb1,
    const float* __restrict__ encW2, const float* __restrict__ encb2,
    const float* __restrict__ Wih,  const float* __restrict__ Whh,
    const float* __restrict__ bih,  const float* __restrict__ bhh,
    float* __restrict__ esum)
{
    __shared__ float ctx_lds[16 * N_FEAT];   // 4 KB
    __shared__ float bufA[16 * 256];         // 16 KB
    __shared__ float bufB[16 * 256];         // 16 KB

    const int tid   = threadIdx.x;
    const int j     = tid & 255;
    const int rh    = tid >> 8;       // 0 or 1
    const int rbase = rh * 8;
    const int r0    = blockIdx.x * 16;

    // ---- stage context rows ----
    for (int t = tid; t < 16 * N_FEAT; t += 512)
        ctx_lds[t] = ctx[r0 * N_FEAT + t];
    __syncthreads();

    // ---- hid = relu(ctx @ encW1 + b1) ----
    {
        float acc[8];
        float b = encb1[j];
        #pragma unroll
        for (int r = 0; r < 8; ++r) acc[r] = b;
        for (int k = 0; k < N_FEAT; ++k) {
            float w = encW1[k * NHID + j];
            #pragma unroll
            for (int r = 0; r < 8; ++r)
                acc[r] = fmaf(ctx_lds[(rbase + r) * N_FEAT + k], w, acc[r]);
        }
        #pragma unroll
        for (int r = 0; r < 8; ++r)
            bufA[(rbase + r) * 256 + j] = fmaxf(acc[r], 0.0f);
    }
    __syncthreads();

    // ---- phi = hid @ encW2 + b2 ----
    {
        float p[8];
        float b = encb2[j];
        #pragma unroll
        for (int r = 0; r < 8; ++r) p[r] = b;
        for (int k = 0; k < NHID; ++k) {
            float w = encW2[k * ENC + j];
            #pragma unroll
            for (int r = 0; r < 8; ++r)
                p[r] = fmaf(bufA[(rbase + r) * 256 + k], w, p[r]);
        }
        __syncthreads();   // all reads of hid done
        #pragma unroll
        for (int r = 0; r < 8; ++r)
            bufA[(rbase + r) * 256 + j] = p[r];
    }
    __syncthreads();

    // ---- x_proj[g][r] for gate column m = g*256 + j ----
    float xp[4][8];
    #pragma unroll
    for (int g = 0; g < 4; ++g) {
        int m = g * 256 + j;
        float b = bih[m] + bhh[m];
        #pragma unroll
        for (int r = 0; r < 8; ++r) xp[g][r] = b;
        const float4* wrow = (const float4*)(Wih + m * ENC);
        for (int k4 = 0; k4 < ENC / 4; ++k4) {
            float4 w = wrow[k4];
            #pragma unroll
            for (int r = 0; r < 8; ++r) {
                const float* ph = &bufA[(rbase + r) * 256 + k4 * 4];
                float v = xp[g][r];
                v = fmaf(ph[0], w.x, v);
                v = fmaf(ph[1], w.y, v);
                v = fmaf(ph[2], w.z, v);
                v = fmaf(ph[3], w.w, v);
                xp[g][r] = v;
            }
        }
    }
    __syncthreads();   // done reading bufA (phi) before step 0 overwrites it

    // ---- LSTM over 32 steps ----
    float h[8], c[8];
    #pragma unroll
    for (int r = 0; r < 8; ++r) { h[r] = 0.0f; c[r] = 0.0f; }

    const float4* wbase0 = (const float4*)(Whh + (0 * 256 + j) * 256);
    const float4* wbase1 = (const float4*)(Whh + (1 * 256 + j) * 256);
    const float4* wbase2 = (const float4*)(Whh + (2 * 256 + j) * 256);
    const float4* wbase3 = (const float4*)(Whh + (3 * 256 + j) * 256);

// 8-wide chunk: 2 float4 per gate -> wA/wB = 4g x 2q float4 = 64 VGPRs total
#define LOADW(dst, c_) do {                                                  \
        _Pragma("unroll") for (int q = 0; q < 2; ++q) {                      \
            dst[0][q] = wbase0[(c_) * 2 + q];                                \
            dst[1][q] = wbase1[(c_) * 2 + q];                                \
            dst[2][q] = wbase2[(c_) * 2 + q];                                \
            dst[3][q] = wbase3[(c_) * 2 + q];                                \
        }                                                                    \
    } while (0)

#define COMPW(w_, c_) do {                                                   \
        _Pragma("unroll") for (int r = 0; r < 8; ++r) {                      \
            const float* hp = &hb[(rbase + r) * 256 + (c_) * 8];             \
            _Pragma("unroll") for (int q = 0; q < 2; ++q) {                  \
                float4 hv = *(const float4*)(hp + q * 4);                    \
                _Pragma("unroll") for (int g = 0; g < 4; ++g) {              \
                    float a = acc[g][r];                                     \
                    a = fmaf(hv.x, w_[g][q].x, a);                           \
                    a = fmaf(hv.y, w_[g][q].y, a);                           \
                    a = fmaf(hv.z, w_[g][q].z, a);                           \
                    a = fmaf(hv.w, w_[g][q].w, a);                           \
                    acc[g][r] = a;                                           \
                }                                                            \
            }                                                                \
        }                                                                    \
    } while (0)

    for (int t = 0; t < TSTEPS; ++t) {
        float* hb = (t & 1) ? bufB : bufA;
        // publish h into LDS (double-buffered -> one barrier per step)
        #pragma unroll
        for (int r = 0; r < 8; ++r)
            hb[(rbase + r) * 256 + j] = h[r];
        __syncthreads();

        float acc[4][8];
        #pragma unroll
        for (int g = 0; g < 4; ++g)
            #pragma unroll
            for (int r = 0; r < 8; ++r) acc[g][r] = xp[g][r];

        // 32 chunks of 8 k-values; ping-pong prefetch keeps 8 dwordx4 loads
        // in flight under each 256-FMA compute phase.
        float4 wA[4][2], wB[4][2];
        LOADW(wA, 0);
        #pragma unroll 1
        for (int c2 = 0; c2 < 16; ++c2) {
            const int c = 2 * c2;
            LOADW(wB, c + 1);              // prefetch odd chunk
            COMPW(wA, c);                  // compute even chunk
            if (c2 < 15) LOADW(wA, c + 2); // prefetch next even chunk
            COMPW(wB, c + 1);              // compute odd chunk
        }

        float hs = 0.0f;
        #pragma unroll
        for (int r = 0; r < 8; ++r) {
            float iv = sigmoidf_(acc[0][r]);
            float fv = sigmoidf_(acc[1][r]);
            float gv = tanhf_(acc[2][r]);
            float ov = sigmoidf_(acc[3][r]);
            c[r] = fv * c[r] + iv * gv;
            h[r] = ov * tanhf_(c[r]);
            hs += h[r];
        }
        atomicAdd(&esum[t * GH + j], hs);
        // no trailing barrier: next step writes the other LDS buffer
    }
#undef LOADW
#undef COMPW
}

// ---------------------------------------------------------------------------
// Kernel C: proj[t][c] = (esum[t]/4096) @ W1_h + att_b1[c]
// Grid: 32 blocks x 256 threads; K split 4 ways, LDS reduce.
// ---------------------------------------------------------------------------
__global__ void proj_kernel(const float* __restrict__ esum,
                            const float* __restrict__ attW1,
                            const float* __restrict__ attb1,
                            float* __restrict__ proj)
{
    __shared__ float part[4][AH];
    const int t   = blockIdx.x;
    const int cix = threadIdx.x & 63;
    const int g   = threadIdx.x >> 6;      // 0..3 -> k range
    float a = 0.0f;
    #pragma unroll 4
    for (int k = g * 64; k < g * 64 + 64; ++k) {
        float e = esum[t * GH + k] * (1.0f / (float)N_TRAIN);
        a = fmaf(e, attW1[(size_t)(N_TRAIN + k) * AH + cix], a);
    }
    part[g][cix] = a;
    __syncthreads();
    if (threadIdx.x < AH)
        proj[t * AH + cix] = part[0][cix] + part[1][cix] + part[2][cix] +
                             part[3][cix] + attb1[cix];
}

// ---------------------------------------------------------------------------
// Kernel D: S_proj (registers) fused with per-step scores.
// Grid: 512 blocks x 256 threads. Block owns 64 antes; thread (a = tid&63,
// ch = tid>>6) accumulates cols [ch*16, ch*16+16).
// S reads hand-pipelined: 16-row register ping-pong prefetch.
// ---------------------------------------------------------------------------
__global__ __launch_bounds__(256, 2) void scores_kernel(
    const float* __restrict__ S,
    const float* __restrict__ attW1,
    const float* __restrict__ proj,
    const float* __restrict__ attw2,
    const float* __restrict__ attb2,
    float* __restrict__ out)
{
    __shared__ float wl[64 * AH];        // 16 KB: 64-row chunk of att_W1
    __shared__ float projl[TSTEPS * AH]; // 8 KB
    __shared__ float w2l[AH];
    __shared__ float part[256];

    const int tid = threadIdx.x;
    const int a0  = blockIdx.x * 64;
    const int ai  = tid & 63;
    const int ch  = tid >> 6;            // 0..3, cols ch*16..+16
    const int a   = a0 + ai;

    float sp[16];
    #pragma unroll
    for (int q = 0; q < 16; ++q) sp[q] = 0.0f;

#define LOADS(dst, base_row) do {                                            \
        _Pragma("unroll") for (int i = 0; i < 16; ++i)                       \
            dst[i] = Scol[(size_t)((base_row) + i) * NANTES];                \
    } while (0)

#define COMPS(src, base_row) do {                                            \
        _Pragma("unroll") for (int i = 0; i < 16; ++i) {                     \
            const float* w = &wl[((base_row) + i) * AH + ch * 16];           \
            float s = src[i];                                                \
            _Pragma("unroll") for (int q = 0; q < 16; ++q)                   \
                sp[q] = fmaf(s, w[q], sp[q]);                                \
        }                                                                    \
    } while (0)

    for (int chunk = 0; chunk < N_TRAIN / 64; ++chunk) {
        __syncthreads();
        {   // stage 64x64 chunk of att_W1 (16 KB, contiguous) as float4
            const float4* src = (const float4*)(attW1 + (size_t)chunk * 64 * AH);
            float4* dstv = (float4*)wl;
            for (int i = tid; i < 64 * AH / 4; i += 256) dstv[i] = src[i];
        }
        __syncthreads();

        const float* Scol = S + (size_t)(chunk * 64) * NANTES + a;
        float sA[16], sB[16];
        LOADS(sA, 0);
        LOADS(sB, 16);
        COMPS(sA, 0);
        LOADS(sA, 32);
        COMPS(sB, 16);
        LOADS(sB, 48);
        COMPS(sA, 32);
        COMPS(sB, 48);
    }
#undef LOADS
#undef COMPS

    for (int t = tid; t < TSTEPS * AH; t += 256) projl[t] = proj[t];
    if (tid < AH) w2l[tid] = attw2[tid];
    __syncthreads();

    const float b2v = attb2[0];
    for (int t = 0; t < TSTEPS; ++t) {
        float s = 0.0f;
        const float* pr  = &projl[t * AH + ch * 16];
        const float* w2p = &w2l[ch * 16];
        #pragma unroll
        for (int q = 0; q < 16; ++q)
            s += fmaxf(sp[q] + pr[q], 0.0f) * w2p[q];
        part[tid] = s;
        __syncthreads();
        if (tid < 64)
            out[(size_t)t * NANTES + a0 + tid] =
                part[tid] + part[tid + 64] + part[tid + 128] + part[tid + 192] + b2v;
        __syncthreads();
    }
}

// ---------------------------------------------------------------------------
// Kernel E: per-step argmax over 32768 antes (first-max semantics).
// ---------------------------------------------------------------------------
__global__ void argmax_kernel(const float* __restrict__ scores,
                              float* __restrict__ out)
{
    __shared__ float bv[256];
    __shared__ int   bidx[256];
    const int t = blockIdx.x, tid = threadIdx.x;
    float best = -INFINITY;
    int   bi   = 0x7fffffff;
    for (int a = tid; a < NANTES; a += 256) {
        float v = scores[(size_t)t * NANTES + a];
        if (v > best) { best = v; bi = a; }
    }
    bv[tid] = best; bidx[tid] = bi;
    __syncthreads();
    for (int s = 128; s > 0; s >>= 1) {
        if (tid < s) {
            if (bv[tid + s] > bv[tid] ||
                (bv[tid + s] == bv[tid] && bidx[tid + s] < bidx[tid])) {
                bv[tid] = bv[tid + s];
                bidx[tid] = bidx[tid + s];
            }
        }
        __syncthreads();
    }
    if (tid == 0)
        out[(size_t)TSTEPS * NANTES + t] = (float)bidx[0];
}

// ---------------------------------------------------------------------------
extern "C" void kernel_launch(void* const* d_in, const int* in_sizes, int n_in,
                              void* d_out, int out_size, void* d_ws, size_t ws_size,
                              hipStream_t stream)
{
    const float* ctx   = (const float*)d_in[0];
    const float* S     = (const float*)d_in[1];
    const float* encW1 = (const float*)d_in[2];
    const float* encb1 = (const float*)d_in[3];
    const float* encW2 = (const float*)d_in[4];
    const float* encb2 = (const float*)d_in[5];
    const float* Wih   = (const float*)d_in[6];
    const float* Whh   = (const float*)d_in[7];
    const float* bih   = (const float*)d_in[8];
    const float* bhh   = (const float*)d_in[9];
    const float* attW1 = (const float*)d_in[10];
    const float* attb1 = (const float*)d_in[11];
    const float* attw2 = (const float*)d_in[12];
    const float* attb2 = (const float*)d_in[13];

    float* esum = (float*)d_ws;                  // 32*256 floats
    float* proj = esum + TSTEPS * GH;            // 32*64 floats
    float* out  = (float*)d_out;

    zero_kernel<<<dim3(8), dim3(256), 0, stream>>>(esum);
    lstm_kernel<<<dim3(N_TRAIN / 16), dim3(512), 0, stream>>>(
        ctx, encW1, encb1, encW2, encb2, Wih, Whh, bih, bhh, esum);
    proj_kernel<<<dim3(TSTEPS), dim3(256), 0, stream>>>(esum, attW1, attb1, proj);
    scores_kernel<<<dim3(NANTES / 64), dim3(256), 0, stream>>>(
        S, attW1, proj, attw2, attb2, out);
    argmax_kernel<<<dim3(TSTEPS), dim3(256), 0, stream>>>(out, out);
}

// Round 4
// 2164.996 us; speedup vs baseline: 3.7085x; 1.3553x over previous
//
#include <hip/hip_runtime.h>
#include <hip/hip_bf16.h>
#include <math.h>

// Problem constants
#define N_TRAIN 4096
#define N_FEAT  64
#define NHID    256
#define ENC     256
#define GH      256
#define AH      64
#define NANTES  32768
#define TSTEPS  32

#define GSTRIDE 1026   // gates LDS row stride (f32); %8==2 -> conflict-free C scatter

typedef __attribute__((ext_vector_type(8))) short bf16x8;
typedef __attribute__((ext_vector_type(4))) float f32x4;

__device__ __forceinline__ float sigmoidf_(float x) {
    return 1.0f / (1.0f + __expf(-x));
}
__device__ __forceinline__ float tanhf_(float x) {
    return 1.0f - 2.0f / (__expf(2.0f * x) + 1.0f);
}
__device__ __forceinline__ unsigned short f2bf_rne(float x) {
    unsigned int u = __float_as_uint(x);
    unsigned int r = u + 0x7FFFu + ((u >> 16) & 1u);
    return (unsigned short)(r >> 16);
}
__device__ __forceinline__ float bf2f(unsigned short b) {
    return __uint_as_float(((unsigned int)b) << 16);
}

// ---------------------------------------------------------------------------
// Kernel 0: zero the e-sum accumulator
// ---------------------------------------------------------------------------
__global__ void zero_kernel(float* __restrict__ esum) {
    int tid = blockIdx.x * blockDim.x + threadIdx.x;
    for (int i = tid; i < TSTEPS * GH; i += gridDim.x * blockDim.x)
        esum[i] = 0.0f;
}

// ---------------------------------------------------------------------------
// Kernel P: pack Whh (1024x256 f32) into MFMA-fragment-ordered bf16 hi/lo.
// Group g = ((ntile*8 + ks)*64 + lane); elems 8: Whh[n0+(lane&15)][ks*32+(lane>>4)*8 + j]
// -> wave load for (ntile,ks) is one contiguous 1 KB chunk.
// ---------------------------------------------------------------------------
__global__ void pack_whh(const float* __restrict__ Whh,
                         unsigned short* __restrict__ hi,
                         unsigned short* __restrict__ lo)
{
    int g = blockIdx.x * 256 + threadIdx.x;      // 0 .. 32767
    if (g >= 64 * 8 * 64) return;
    int lane  = g & 63;
    int ks    = (g >> 6) & 7;
    int ntile = g >> 9;
    int n  = ntile * 16 + (lane & 15);
    int k0 = ks * 32 + (lane >> 4) * 8;
    const float* src = Whh + n * 256 + k0;
    #pragma unroll
    for (int j = 0; j < 8; ++j) {
        float x = src[j];
        unsigned short h16 = f2bf_rne(x);
        float l = x - bf2f(h16);
        hi[g * 8 + j] = h16;
        lo[g * 8 + j] = f2bf_rne(l);
    }
}

// ---------------------------------------------------------------------------
// Kernel A: fused encoder -> x_proj -> 32-step MFMA LSTM -> per-step h sums
// Grid: 256 blocks x 512 threads (8 waves). Block owns 16 rows.
// MFMA phase: wave w owns gate cols [w*128, w*128+128): 8 n-tiles, M=16, K=256.
// 3-term bf16 split: Ah*Bh + Al*Bh + Ah*Bl  (error ~1e-4 rel).
// Pointwise phase: thread (j=tid&255, rh=tid>>8) owns hidden col j x 8 rows.
// ---------------------------------------------------------------------------
__global__ __launch_bounds__(512, 1) void lstm_kernel(
    const float* __restrict__ ctx,
    const float* __restrict__ encW1, const float* __restrict__ encb1,
    const float* __restrict__ encW2, const float* __restrict__ encb2,
    const float* __restrict__ Wih,
    const float* __restrict__ bih,  const float* __restrict__ bhh,
    const unsigned short* __restrict__ Wph,
    const unsigned short* __restrict__ Wpl,
    float* __restrict__ esum)
{
    __shared__ float gates[16 * GSTRIDE];  // 65664 B; setup aliases inside
    __shared__ short hhi[16 * 256];        // 8 KB, XOR-swizzled k
    __shared__ short hlo[16 * 256];        // 8 KB

    float* bufA = gates;                 // 16*256 f32 (setup)
    float* bufB = gates + 16 * 256;      // 16*256 f32 (setup, unused but kept)
    float* ctxl = gates + 2 * 16 * 256;  // 16*64 f32

    const int tid   = threadIdx.x;
    const int j     = tid & 255;
    const int rh    = tid >> 8;
    const int rbase = rh * 8;
    const int r0    = blockIdx.x * 16;

    // ==================== setup (f32, one-time) ====================
    for (int t = tid; t < 16 * N_FEAT; t += 512)
        ctxl[t] = ctx[r0 * N_FEAT + t];
    __syncthreads();

    {   // hid = relu(ctx @ encW1 + b1) -> bufA
        float acc[8];
        float b = encb1[j];
        #pragma unroll
        for (int r = 0; r < 8; ++r) acc[r] = b;
        for (int k = 0; k < N_FEAT; ++k) {
            float w = encW1[k * NHID + j];
            #pragma unroll
            for (int r = 0; r < 8; ++r)
                acc[r] = fmaf(ctxl[(rbase + r) * N_FEAT + k], w, acc[r]);
        }
        #pragma unroll
        for (int r = 0; r < 8; ++r)
            bufA[(rbase + r) * 256 + j] = fmaxf(acc[r], 0.0f);
    }
    __syncthreads();

    {   // phi = hid @ encW2 + b2 -> bufB
        float p[8];
        float b = encb2[j];
        #pragma unroll
        for (int r = 0; r < 8; ++r) p[r] = b;
        for (int k = 0; k < NHID; ++k) {
            float w = encW2[k * ENC + j];
            #pragma unroll
            for (int r = 0; r < 8; ++r)
                p[r] = fmaf(bufA[(rbase + r) * 256 + k], w, p[r]);
        }
        __syncthreads();
        #pragma unroll
        for (int r = 0; r < 8; ++r)
            bufB[(rbase + r) * 256 + j] = p[r];
    }
    __syncthreads();

    // xp[g][r] in registers (reads phi from bufB)
    float xp[4][8];
    #pragma unroll
    for (int g = 0; g < 4; ++g) {
        int m = g * 256 + j;
        float b = bih[m] + bhh[m];
        #pragma unroll
        for (int r = 0; r < 8; ++r) xp[g][r] = b;
        const float4* wrow = (const float4*)(Wih + m * ENC);
        for (int k4 = 0; k4 < ENC / 4; ++k4) {
            float4 w = wrow[k4];
            #pragma unroll
            for (int r = 0; r < 8; ++r) {
                const float* ph = &bufB[(rbase + r) * 256 + k4 * 4];
                float v = xp[g][r];
                v = fmaf(ph[0], w.x, v);
                v = fmaf(ph[1], w.y, v);
                v = fmaf(ph[2], w.z, v);
                v = fmaf(ph[3], w.w, v);
                xp[g][r] = v;
            }
        }
    }
    __syncthreads();   // phi fully consumed; gates buffer free now

    // scatter xp into gates[r][n] layout; zero h LDS
    #pragma unroll
    for (int g = 0; g < 4; ++g)
        #pragma unroll
        for (int r = 0; r < 8; ++r)
            gates[(rbase + r) * GSTRIDE + g * 256 + j] = xp[g][r];
    for (int i = tid; i < 16 * 256; i += 512) { hhi[i] = 0; hlo[i] = 0; }
    __syncthreads();

    // ==================== MFMA-phase constants ====================
    const int w    = tid >> 6;        // wave 0..7
    const int l    = tid & 63;
    const int col  = l & 15;          // tile col / A row
    const int kp   = l >> 4;          // 0..3
    const int arow = col;             // A row = lane&15
    const int asw  = (arow & 7) << 3; // short-unit XOR swizzle

    // xp fragments in C layout: xpf[nt][q] = gates[(kp*4+q)][w*128+nt*16+col]
    f32x4 xpf[8];
    #pragma unroll
    for (int nt = 0; nt < 8; ++nt)
        #pragma unroll
        for (int q = 0; q < 4; ++q)
            xpf[nt][q] = gates[(kp * 4 + q) * GSTRIDE + w * 128 + nt * 16 + col];
    __syncthreads();

    // B element offset for (nt, ks): (((w*8+nt)*8+ks)*64 + l)*8
    const unsigned short* Bh = Wph + (size_t)l * 8;
    const unsigned short* Bl = Wpl + (size_t)l * 8;

#define LOADB(dh, dl, ks_) do {                                              \
        _Pragma("unroll") for (int nt = 0; nt < 8; ++nt) {                   \
            size_t off = (size_t)(((w * 8 + nt) * 8 + (ks_)) * 64) * 8;      \
            dh[nt] = *(const bf16x8*)(Bh + off);                             \
            dl[nt] = *(const bf16x8*)(Bl + off);                             \
        }                                                                    \
    } while (0)

#define DOMFMA(bh_, bl_, ks_) do {                                           \
        bf16x8 ah = *(const bf16x8*)&hhi[arow * 256 +                        \
                        (((ks_) * 32 + kp * 8) ^ asw)];                      \
        bf16x8 al = *(const bf16x8*)&hlo[arow * 256 +                        \
                        (((ks_) * 32 + kp * 8) ^ asw)];                      \
        _Pragma("unroll") for (int nt = 0; nt < 8; ++nt) {                   \
            acc[nt] = __builtin_amdgcn_mfma_f32_16x16x32_bf16(ah, bh_[nt], acc[nt], 0, 0, 0); \
            acc[nt] = __builtin_amdgcn_mfma_f32_16x16x32_bf16(al, bh_[nt], acc[nt], 0, 0, 0); \
            acc[nt] = __builtin_amdgcn_mfma_f32_16x16x32_bf16(ah, bl_[nt], acc[nt], 0, 0, 0); \
        }                                                                    \
    } while (0)

    // ==================== LSTM loop ====================
    float c[8];
    #pragma unroll
    for (int r = 0; r < 8; ++r) c[r] = 0.0f;

    for (int t = 0; t < TSTEPS; ++t) {
        // ---- MFMA phase: gates_pre = h @ Whh^T + xp ----
        f32x4 acc[8];
        #pragma unroll
        for (int nt = 0; nt < 8; ++nt) acc[nt] = xpf[nt];

        bf16x8 bh0[8], bl0[8], bh1[8], bl1[8];
        LOADB(bh0, bl0, 0);
        LOADB(bh1, bl1, 1);
        DOMFMA(bh0, bl0, 0);
        LOADB(bh0, bl0, 2);
        DOMFMA(bh1, bl1, 1);
        LOADB(bh1, bl1, 3);
        DOMFMA(bh0, bl0, 2);
        LOADB(bh0, bl0, 4);
        DOMFMA(bh1, bl1, 3);
        LOADB(bh1, bl1, 5);
        DOMFMA(bh0, bl0, 4);
        LOADB(bh0, bl0, 6);
        DOMFMA(bh1, bl1, 5);
        LOADB(bh1, bl1, 7);
        DOMFMA(bh0, bl0, 6);
        DOMFMA(bh1, bl1, 7);

        // scatter gate pre-activations to LDS
        #pragma unroll
        for (int nt = 0; nt < 8; ++nt)
            #pragma unroll
            for (int q = 0; q < 4; ++q)
                gates[(kp * 4 + q) * GSTRIDE + w * 128 + nt * 16 + col] = acc[nt][q];
        __syncthreads();

        // ---- pointwise phase ----
        float hs = 0.0f;
        #pragma unroll
        for (int r = 0; r < 8; ++r) {
            int rr = rbase + r;
            float iv = sigmoidf_(gates[rr * GSTRIDE + j]);
            float fv = sigmoidf_(gates[rr * GSTRIDE + 256 + j]);
            float gv = tanhf_   (gates[rr * GSTRIDE + 512 + j]);
            float ov = sigmoidf_(gates[rr * GSTRIDE + 768 + j]);
            c[r] = fv * c[r] + iv * gv;
            float h = ov * tanhf_(c[r]);
            hs += h;
            unsigned short h16 = f2bf_rne(h);
            float lof = h - bf2f(h16);
            int sidx = rr * 256 + (j ^ ((rr & 7) << 3));
            hhi[sidx] = (short)h16;
            hlo[sidx] = (short)f2bf_rne(lof);
        }
        atomicAdd(&esum[t * GH + j], hs);
        __syncthreads();
    }
#undef LOADB
#undef DOMFMA
}

// ---------------------------------------------------------------------------
// Kernel C: proj[t][c] = (esum[t]/4096) @ W1_h + att_b1[c]
// ---------------------------------------------------------------------------
__global__ void proj_kernel(const float* __restrict__ esum,
                            const float* __restrict__ attW1,
                            const float* __restrict__ attb1,
                            float* __restrict__ proj)
{
    __shared__ float part[4][AH];
    const int t   = blockIdx.x;
    const int cix = threadIdx.x & 63;
    const int g   = threadIdx.x >> 6;
    float a = 0.0f;
    #pragma unroll 4
    for (int k = g * 64; k < g * 64 + 64; ++k) {
        float e = esum[t * GH + k] * (1.0f / (float)N_TRAIN);
        a = fmaf(e, attW1[(size_t)(N_TRAIN + k) * AH + cix], a);
    }
    part[g][cix] = a;
    __syncthreads();
    if (threadIdx.x < AH)
        proj[t * AH + cix] = part[0][cix] + part[1][cix] + part[2][cix] +
                             part[3][cix] + attb1[cix];
}

// ---------------------------------------------------------------------------
// Kernel D: S_proj (registers) fused with per-step scores.
// ---------------------------------------------------------------------------
__global__ __launch_bounds__(256, 2) void scores_kernel(
    const float* __restrict__ S,
    const float* __restrict__ attW1,
    const float* __restrict__ proj,
    const float* __restrict__ attw2,
    const float* __restrict__ attb2,
    float* __restrict__ out)
{
    __shared__ float wl[64 * AH];
    __shared__ float projl[TSTEPS * AH];
    __shared__ float w2l[AH];
    __shared__ float part[256];

    const int tid = threadIdx.x;
    const int a0  = blockIdx.x * 64;
    const int ai  = tid & 63;
    const int ch  = tid >> 6;
    const int a   = a0 + ai;

    float sp[16];
    #pragma unroll
    for (int q = 0; q < 16; ++q) sp[q] = 0.0f;

#define LOADS(dst, base_row) do {                                            \
        _Pragma("unroll") for (int i = 0; i < 16; ++i)                       \
            dst[i] = Scol[(size_t)((base_row) + i) * NANTES];                \
    } while (0)

#define COMPS(src, base_row) do {                                            \
        _Pragma("unroll") for (int i = 0; i < 16; ++i) {                     \
            const float* w = &wl[((base_row) + i) * AH + ch * 16];           \
            float s = src[i];                                                \
            _Pragma("unroll") for (int q = 0; q < 16; ++q)                   \
                sp[q] = fmaf(s, w[q], sp[q]);                                \
        }                                                                    \
    } while (0)

    for (int chunk = 0; chunk < N_TRAIN / 64; ++chunk) {
        __syncthreads();
        {
            const float4* src = (const float4*)(attW1 + (size_t)chunk * 64 * AH);
            float4* dstv = (float4*)wl;
            for (int i = tid; i < 64 * AH / 4; i += 256) dstv[i] = src[i];
        }
        __syncthreads();

        const float* Scol = S + (size_t)(chunk * 64) * NANTES + a;
        float sA[16], sB[16];
        LOADS(sA, 0);
        LOADS(sB, 16);
        COMPS(sA, 0);
        LOADS(sA, 32);
        COMPS(sB, 16);
        LOADS(sB, 48);
        COMPS(sA, 32);
        COMPS(sB, 48);
    }
#undef LOADS
#undef COMPS

    for (int t = tid; t < TSTEPS * AH; t += 256) projl[t] = proj[t];
    if (tid < AH) w2l[tid] = attw2[tid];
    __syncthreads();

    const float b2v = attb2[0];
    for (int t = 0; t < TSTEPS; ++t) {
        float s = 0.0f;
        const float* pr  = &projl[t * AH + ch * 16];
        const float* w2p = &w2l[ch * 16];
        #pragma unroll
        for (int q = 0; q < 16; ++q)
            s += fmaxf(sp[q] + pr[q], 0.0f) * w2p[q];
        part[tid] = s;
        __syncthreads();
        if (tid < 64)
            out[(size_t)t * NANTES + a0 + tid] =
                part[tid] + part[tid + 64] + part[tid + 128] + part[tid + 192] + b2v;
        __syncthreads();
    }
}

// ---------------------------------------------------------------------------
// Kernel E: per-step argmax (first-max semantics).
// ---------------------------------------------------------------------------
__global__ void argmax_kernel(const float* __restrict__ scores,
                              float* __restrict__ out)
{
    __shared__ float bv[256];
    __shared__ int   bidx[256];
    const int t = blockIdx.x, tid = threadIdx.x;
    float best = -INFINITY;
    int   bi   = 0x7fffffff;
    for (int a = tid; a < NANTES; a += 256) {
        float v = scores[(size_t)t * NANTES + a];
        if (v > best) { best = v; bi = a; }
    }
    bv[tid] = best; bidx[tid] = bi;
    __syncthreads();
    for (int s = 128; s > 0; s >>= 1) {
        if (tid < s) {
            if (bv[tid + s] > bv[tid] ||
                (bv[tid + s] == bv[tid] && bidx[tid + s] < bidx[tid])) {
                bv[tid] = bv[tid + s];
                bidx[tid] = bidx[tid + s];
            }
        }
        __syncthreads();
    }
    if (tid == 0)
        out[(size_t)TSTEPS * NANTES + t] = (float)bidx[0];
}

// ---------------------------------------------------------------------------
extern "C" void kernel_launch(void* const* d_in, const int* in_sizes, int n_in,
                              void* d_out, int out_size, void* d_ws, size_t ws_size,
                              hipStream_t stream)
{
    const float* ctx   = (const float*)d_in[0];
    const float* S     = (const float*)d_in[1];
    const float* encW1 = (const float*)d_in[2];
    const float* encb1 = (const float*)d_in[3];
    const float* encW2 = (const float*)d_in[4];
    const float* encb2 = (const float*)d_in[5];
    const float* Wih   = (const float*)d_in[6];
    const float* Whh   = (const float*)d_in[7];
    const float* bih   = (const float*)d_in[8];
    const float* bhh   = (const float*)d_in[9];
    const float* attW1 = (const float*)d_in[10];
    const float* attb1 = (const float*)d_in[11];
    const float* attw2 = (const float*)d_in[12];
    const float* attb2 = (const float*)d_in[13];

    char* ws = (char*)d_ws;
    float* esum = (float*)ws;                                   // 32 KB
    float* proj = (float*)(ws + 32768);                         // 8 KB
    unsigned short* Wph = (unsigned short*)(ws + 40960);        // 512 KB
    unsigned short* Wpl = (unsigned short*)(ws + 40960 + 524288); // 512 KB
    float* out  = (float*)d_out;

    zero_kernel<<<dim3(8), dim3(256), 0, stream>>>(esum);
    pack_whh<<<dim3(128), dim3(256), 0, stream>>>(Whh, Wph, Wpl);
    lstm_kernel<<<dim3(N_TRAIN / 16), dim3(512), 0, stream>>>(
        ctx, encW1, encb1, encW2, encb2, Wih, bih, bhh, Wph, Wpl, esum);
    proj_kernel<<<dim3(TSTEPS), dim3(256), 0, stream>>>(esum, attW1, attb1, proj);
    scores_kernel<<<dim3(NANTES / 64), dim3(256), 0, stream>>>(
        S, attW1, proj, attw2, attb2, out);
    argmax_kernel<<<dim3(TSTEPS), dim3(256), 0, stream>>>(out, out);
}

// Round 5
// 1909.045 us; speedup vs baseline: 4.2057x; 1.1341x over previous
//
#include <hip/hip_runtime.h>
#include <hip/hip_bf16.h>
#include <math.h>

// Problem constants
#define N_TRAIN 4096
#define N_FEAT  64
#define NHID    256
#define ENC     256
#define GH      256
#define AH      64
#define NANTES  32768
#define TSTEPS  32

#define XSTR 1026   // xp-stage LDS row stride (f32); %32==2 -> <=2-way on gather

typedef __attribute__((ext_vector_type(8))) short bf16x8;
typedef __attribute__((ext_vector_type(4))) float f32x4;

__device__ __forceinline__ float sigmoidf_(float x) {
    return 1.0f / (1.0f + __expf(-x));
}
__device__ __forceinline__ float tanhf_(float x) {
    return 1.0f - 2.0f / (__expf(2.0f * x) + 1.0f);
}
__device__ __forceinline__ unsigned short f2bf_rne(float x) {
    unsigned int u = __float_as_uint(x);
    unsigned int r = u + 0x7FFFu + ((u >> 16) & 1u);
    return (unsigned short)(r >> 16);
}
__device__ __forceinline__ float bf2f(unsigned short b) {
    return __uint_as_float(((unsigned int)b) << 16);
}

// ---------------------------------------------------------------------------
// Kernel 0: zero the e-sum accumulator
// ---------------------------------------------------------------------------
__global__ void zero_kernel(float* __restrict__ esum) {
    int tid = blockIdx.x * blockDim.x + threadIdx.x;
    for (int i = tid; i < TSTEPS * GH; i += gridDim.x * blockDim.x)
        esum[i] = 0.0f;
}

// ---------------------------------------------------------------------------
// Kernel P: pack Whh (1024x256 f32) into MFMA-fragment-ordered bf16 hi/lo.
// Group g = ((ntile*8 + ks)*64 + lane); 8 elems: Whh[nt*16+(lane&15)][ks*32+(lane>>4)*8 + j]
// -> wave load for (ntile,ks) is one contiguous 1 KB chunk.
// ---------------------------------------------------------------------------
__global__ void pack_whh(const float* __restrict__ Whh,
                         unsigned short* __restrict__ hi,
                         unsigned short* __restrict__ lo)
{
    int g = blockIdx.x * 256 + threadIdx.x;      // 0 .. 32767
    if (g >= 64 * 8 * 64) return;
    int lane  = g & 63;
    int ks    = (g >> 6) & 7;
    int ntile = g >> 9;
    int n  = ntile * 16 + (lane & 15);
    int k0 = ks * 32 + (lane >> 4) * 8;
    const float* src = Whh + n * 256 + k0;
    #pragma unroll
    for (int j = 0; j < 8; ++j) {
        float x = src[j];
        unsigned short h16 = f2bf_rne(x);
        float l = x - bf2f(h16);
        hi[g * 8 + j] = h16;
        lo[g * 8 + j] = f2bf_rne(l);
    }
}

// ---------------------------------------------------------------------------
// Kernel A: fused encoder -> x_proj -> 32-step MFMA LSTM -> per-step h sums
// Grid: 256 blocks x 512 threads (8 waves). Block owns 16 rows (M=16).
// Wave w owns hidden cols [w*32, w*32+32): n-tiles nt(g,u) = 16g + 2w + u
// -> each wave holds matching i/f/g/o C-fragments; pointwise is fully
// register-resident (no gates LDS, one barrier per step).
// 3-term bf16 split: Ah*Bh + Al*Bh + Ah*Bl.
// ---------------------------------------------------------------------------
__global__ __launch_bounds__(512, 2) void lstm_kernel(
    const float* __restrict__ ctx,
    const float* __restrict__ encW1, const float* __restrict__ encb1,
    const float* __restrict__ encW2, const float* __restrict__ encb2,
    const float* __restrict__ Wih,
    const float* __restrict__ bih,  const float* __restrict__ bhh,
    const unsigned short* __restrict__ Wph,
    const unsigned short* __restrict__ Wpl,
    float* __restrict__ esum)
{
    __shared__ float xps[16 * XSTR];       // 65664 B; aliased in setup
    __shared__ short hhi[2][16 * 256];     // 16 KB, XOR-swizzled cols
    __shared__ short hlo[2][16 * 256];     // 16 KB

    float* bufA = xps;                 // 16*256 f32 (setup: hid)
    float* bufB = xps + 16 * 256;      // 16*256 f32 (setup: phi)
    float* ctxl = xps + 32 * 256;      // 16*64 f32

    const int tid   = threadIdx.x;
    const int j     = tid & 255;
    const int rh    = tid >> 8;
    const int rbase = rh * 8;
    const int r0    = blockIdx.x * 16;

    // ==================== setup (f32, one-time) ====================
    for (int t = tid; t < 16 * N_FEAT; t += 512)
        ctxl[t] = ctx[r0 * N_FEAT + t];
    __syncthreads();

    {   // hid = relu(ctx @ encW1 + b1) -> bufA
        float acc[8];
        float b = encb1[j];
        #pragma unroll
        for (int r = 0; r < 8; ++r) acc[r] = b;
        for (int k = 0; k < N_FEAT; ++k) {
            float w = encW1[k * NHID + j];
            #pragma unroll
            for (int r = 0; r < 8; ++r)
                acc[r] = fmaf(ctxl[(rbase + r) * N_FEAT + k], w, acc[r]);
        }
        #pragma unroll
        for (int r = 0; r < 8; ++r)
            bufA[(rbase + r) * 256 + j] = fmaxf(acc[r], 0.0f);
    }
    __syncthreads();

    {   // phi = hid @ encW2 + b2 -> bufB
        float p[8];
        float b = encb2[j];
        #pragma unroll
        for (int r = 0; r < 8; ++r) p[r] = b;
        for (int k = 0; k < NHID; ++k) {
            float w = encW2[k * ENC + j];
            #pragma unroll
            for (int r = 0; r < 8; ++r)
                p[r] = fmaf(bufA[(rbase + r) * 256 + k], w, p[r]);
        }
        __syncthreads();
        #pragma unroll
        for (int r = 0; r < 8; ++r)
            bufB[(rbase + r) * 256 + j] = p[r];
    }
    __syncthreads();

    // xp[g][r] in registers (reads phi from bufB)
    float xp[4][8];
    #pragma unroll
    for (int g = 0; g < 4; ++g) {
        int m = g * 256 + j;
        float b = bih[m] + bhh[m];
        #pragma unroll
        for (int r = 0; r < 8; ++r) xp[g][r] = b;
        const float4* wrow = (const float4*)(Wih + m * ENC);
        for (int k4 = 0; k4 < ENC / 4; ++k4) {
            float4 wv = wrow[k4];
            #pragma unroll
            for (int r = 0; r < 8; ++r) {
                const float* ph = &bufB[(rbase + r) * 256 + k4 * 4];
                float v = xp[g][r];
                v = fmaf(ph[0], wv.x, v);
                v = fmaf(ph[1], wv.y, v);
                v = fmaf(ph[2], wv.z, v);
                v = fmaf(ph[3], wv.w, v);
                xp[g][r] = v;
            }
        }
    }
    __syncthreads();   // phi consumed; xps free

    // scatter xp into xps[row][gatecol]; zero h buffer 0
    #pragma unroll
    for (int g = 0; g < 4; ++g)
        #pragma unroll
        for (int r = 0; r < 8; ++r)
            xps[(rbase + r) * XSTR + g * 256 + j] = xp[g][r];
    for (int i = tid; i < 16 * 256; i += 512) { hhi[0][i] = 0; hlo[0][i] = 0; }
    __syncthreads();

    // ==================== MFMA-phase constants ====================
    const int w    = tid >> 6;        // wave 0..7
    const int l    = tid & 63;
    const int col  = l & 15;          // N-col within tile / A-row
    const int kp   = l >> 4;          // 0..3
    const int arow = col;
    const int asw  = (arow & 7) << 3; // short-unit XOR swizzle

    // xpf[g][u] in C layout: row = kp*4+q, gatecol = g*256 + w*32 + u*16 + col
    f32x4 xpf[4][2];
    #pragma unroll
    for (int g = 0; g < 4; ++g)
        #pragma unroll
        for (int u = 0; u < 2; ++u)
            #pragma unroll
            for (int q = 0; q < 4; ++q)
                xpf[g][u][q] = xps[(kp * 4 + q) * XSTR + g * 256 + w * 32 + u * 16 + col];

    // B pointers: chunk for (nt, ks) at (((nt*8)+ks)*64 + l)*8 shorts
    const unsigned short* Bh = Wph + (size_t)l * 8;
    const unsigned short* Bl = Wpl + (size_t)l * 8;

#define LOADB(dh, dl, ks_) do {                                              \
        _Pragma("unroll") for (int g = 0; g < 4; ++g)                        \
        _Pragma("unroll") for (int u = 0; u < 2; ++u) {                      \
            size_t off = (size_t)(((16 * g + 2 * w + u) * 8 + (ks_)) * 64) * 8; \
            dh[g][u] = *(const bf16x8*)(Bh + off);                           \
            dl[g][u] = *(const bf16x8*)(Bl + off);                           \
        }                                                                    \
    } while (0)

#define DOMFMA(bh_, bl_, ks_) do {                                           \
        bf16x8 ah = *(const bf16x8*)&Ahi[arow * 256 +                        \
                        (((ks_) * 32 + kp * 8) ^ asw)];                      \
        bf16x8 al = *(const bf16x8*)&Alo[arow * 256 +                        \
                        (((ks_) * 32 + kp * 8) ^ asw)];                      \
        _Pragma("unroll") for (int g = 0; g < 4; ++g)                        \
        _Pragma("unroll") for (int u = 0; u < 2; ++u) {                      \
            acc[g][u] = __builtin_amdgcn_mfma_f32_16x16x32_bf16(ah, bl_[g][u], acc[g][u], 0, 0, 0); \
            acc[g][u] = __builtin_amdgcn_mfma_f32_16x16x32_bf16(al, bh_[g][u], acc[g][u], 0, 0, 0); \
            acc[g][u] = __builtin_amdgcn_mfma_f32_16x16x32_bf16(ah, bh_[g][u], acc[g][u], 0, 0, 0); \
        }                                                                    \
    } while (0)

    // ==================== LSTM loop ====================
    float c[2][4];
    #pragma unroll
    for (int u = 0; u < 2; ++u)
        #pragma unroll
        for (int q = 0; q < 4; ++q) c[u][q] = 0.0f;

    for (int t = 0; t < TSTEPS; ++t) {
        const short* Ahi = hhi[t & 1];
        const short* Alo = hlo[t & 1];
        short* Nhi = hhi[(t + 1) & 1];
        short* Nlo = hlo[(t + 1) & 1];

        f32x4 acc[4][2];
        #pragma unroll
        for (int g = 0; g < 4; ++g)
            #pragma unroll
            for (int u = 0; u < 2; ++u) acc[g][u] = xpf[g][u];

        bf16x8 b0h[4][2], b0l[4][2], b1h[4][2], b1l[4][2];
        LOADB(b0h, b0l, 0);
        LOADB(b1h, b1l, 1);
        DOMFMA(b0h, b0l, 0);
        LOADB(b0h, b0l, 2);
        DOMFMA(b1h, b1l, 1);
        LOADB(b1h, b1l, 3);
        DOMFMA(b0h, b0l, 2);
        LOADB(b0h, b0l, 4);
        DOMFMA(b1h, b1l, 3);
        LOADB(b1h, b1l, 5);
        DOMFMA(b0h, b0l, 4);
        LOADB(b0h, b0l, 6);
        DOMFMA(b1h, b1l, 5);
        LOADB(b1h, b1l, 7);
        DOMFMA(b0h, b0l, 6);
        DOMFMA(b1h, b1l, 7);

        // ---- register pointwise: lane holds rows kp*4+q, cols w*32+u*16+col
        float su[2] = {0.0f, 0.0f};
        #pragma unroll
        for (int u = 0; u < 2; ++u) {
            #pragma unroll
            for (int q = 0; q < 4; ++q) {
                float iv = sigmoidf_(acc[0][u][q]);
                float fv = sigmoidf_(acc[1][u][q]);
                float gv = tanhf_   (acc[2][u][q]);
                float ov = sigmoidf_(acc[3][u][q]);
                c[u][q] = fv * c[u][q] + iv * gv;
                float hv = ov * tanhf_(c[u][q]);
                su[u] += hv;
                unsigned short h16 = f2bf_rne(hv);
                float lof = hv - bf2f(h16);
                int row  = kp * 4 + q;
                int hcol = w * 32 + u * 16 + col;
                int sidx = row * 256 + (hcol ^ ((row & 7) << 3));
                Nhi[sidx] = (short)h16;
                Nlo[sidx] = (short)f2bf_rne(lof);
            }
        }
        // e-sum: reduce over the 16 rows (lanes sharing col within wave)
        #pragma unroll
        for (int u = 0; u < 2; ++u) {
            float v = su[u];
            v += __shfl_xor(v, 16);
            v += __shfl_xor(v, 32);
            if (l < 16)
                atomicAdd(&esum[t * GH + w * 32 + u * 16 + l], v);
        }
        __syncthreads();
    }
#undef LOADB
#undef DOMFMA
}

// ---------------------------------------------------------------------------
// Kernel C: proj[t][c] = (esum[t]/4096) @ W1_h + att_b1[c]
// ---------------------------------------------------------------------------
__global__ void proj_kernel(const float* __restrict__ esum,
                            const float* __restrict__ attW1,
                            const float* __restrict__ attb1,
                            float* __restrict__ proj)
{
    __shared__ float part[4][AH];
    const int t   = blockIdx.x;
    const int cix = threadIdx.x & 63;
    const int g   = threadIdx.x >> 6;
    float a = 0.0f;
    #pragma unroll 4
    for (int k = g * 64; k < g * 64 + 64; ++k) {
        float e = esum[t * GH + k] * (1.0f / (float)N_TRAIN);
        a = fmaf(e, attW1[(size_t)(N_TRAIN + k) * AH + cix], a);
    }
    part[g][cix] = a;
    __syncthreads();
    if (threadIdx.x < AH)
        proj[t * AH + cix] = part[0][cix] + part[1][cix] + part[2][cix] +
                             part[3][cix] + attb1[cix];
}

// ---------------------------------------------------------------------------
// Kernel D: S_proj (registers) fused with per-step scores.
// ---------------------------------------------------------------------------
__global__ __launch_bounds__(256, 2) void scores_kernel(
    const float* __restrict__ S,
    const float* __restrict__ attW1,
    const float* __restrict__ proj,
    const float* __restrict__ attw2,
    const float* __restrict__ attb2,
    float* __restrict__ out)
{
    __shared__ float wl[64 * AH];
    __shared__ float projl[TSTEPS * AH];
    __shared__ float w2l[AH];
    __shared__ float part[256];

    const int tid = threadIdx.x;
    const int a0  = blockIdx.x * 64;
    const int ai  = tid & 63;
    const int ch  = tid >> 6;
    const int a   = a0 + ai;

    float sp[16];
    #pragma unroll
    for (int q = 0; q < 16; ++q) sp[q] = 0.0f;

#define LOADS(dst, base_row) do {                                            \
        _Pragma("unroll") for (int i = 0; i < 16; ++i)                       \
            dst[i] = Scol[(size_t)((base_row) + i) * NANTES];                \
    } while (0)

#define COMPS(src, base_row) do {                                            \
        _Pragma("unroll") for (int i = 0; i < 16; ++i) {                     \
            const float* wp = &wl[((base_row) + i) * AH + ch * 16];          \
            float s = src[i];                                                \
            _Pragma("unroll") for (int q = 0; q < 16; ++q)                   \
                sp[q] = fmaf(s, wp[q], sp[q]);                               \
        }                                                                    \
    } while (0)

    for (int chunk = 0; chunk < N_TRAIN / 64; ++chunk) {
        __syncthreads();
        {
            const float4* src = (const float4*)(attW1 + (size_t)chunk * 64 * AH);
            float4* dstv = (float4*)wl;
            for (int i = tid; i < 64 * AH / 4; i += 256) dstv[i] = src[i];
        }
        __syncthreads();

        const float* Scol = S + (size_t)(chunk * 64) * NANTES + a;
        float sA[16], sB[16];
        LOADS(sA, 0);
        LOADS(sB, 16);
        COMPS(sA, 0);
        LOADS(sA, 32);
        COMPS(sB, 16);
        LOADS(sB, 48);
        COMPS(sA, 32);
        COMPS(sB, 48);
    }
#undef LOADS
#undef COMPS

    for (int t = tid; t < TSTEPS * AH; t += 256) projl[t] = proj[t];
    if (tid < AH) w2l[tid] = attw2[tid];
    __syncthreads();

    const float b2v = attb2[0];
    for (int t = 0; t < TSTEPS; ++t) {
        float s = 0.0f;
        const float* pr  = &projl[t * AH + ch * 16];
        const float* w2p = &w2l[ch * 16];
        #pragma unroll
        for (int q = 0; q < 16; ++q)
            s += fmaxf(sp[q] + pr[q], 0.0f) * w2p[q];
        part[tid] = s;
        __syncthreads();
        if (tid < 64)
            out[(size_t)t * NANTES + a0 + tid] =
                part[tid] + part[tid + 64] + part[tid + 128] + part[tid + 192] + b2v;
        __syncthreads();
    }
}

// ---------------------------------------------------------------------------
// Kernel E: per-step argmax (first-max semantics).
// ---------------------------------------------------------------------------
__global__ void argmax_kernel(const float* __restrict__ scores,
                              float* __restrict__ out)
{
    __shared__ float bv[256];
    __shared__ int   bidx[256];
    const int t = blockIdx.x, tid = threadIdx.x;
    float best = -INFINITY;
    int   bi   = 0x7fffffff;
    for (int a = tid; a < NANTES; a += 256) {
        float v = scores[(size_t)t * NANTES + a];
        if (v > best) { best = v; bi = a; }
    }
    bv[tid] = best; bidx[tid] = bi;
    __syncthreads();
    for (int s = 128; s > 0; s >>= 1) {
        if (tid < s) {
            if (bv[tid + s] > bv[tid] ||
                (bv[tid + s] == bv[tid] && bidx[tid + s] < bidx[tid])) {
                bv[tid] = bv[tid + s];
                bidx[tid] = bidx[tid + s];
            }
        }
        __syncthreads();
    }
    if (tid == 0)
        out[(size_t)TSTEPS * NANTES + t] = (float)bidx[0];
}

// ---------------------------------------------------------------------------
extern "C" void kernel_launch(void* const* d_in, const int* in_sizes, int n_in,
                              void* d_out, int out_size, void* d_ws, size_t ws_size,
                              hipStream_t stream)
{
    const float* ctx   = (const float*)d_in[0];
    const float* S     = (const float*)d_in[1];
    const float* encW1 = (const float*)d_in[2];
    const float* encb1 = (const float*)d_in[3];
    const float* encW2 = (const float*)d_in[4];
    const float* encb2 = (const float*)d_in[5];
    const float* Wih   = (const float*)d_in[6];
    const float* Whh   = (const float*)d_in[7];
    const float* bih   = (const float*)d_in[8];
    const float* bhh   = (const float*)d_in[9];
    const float* attW1 = (const float*)d_in[10];
    const float* attb1 = (const float*)d_in[11];
    const float* attw2 = (const float*)d_in[12];
    const float* attb2 = (const float*)d_in[13];

    char* ws = (char*)d_ws;
    float* esum = (float*)ws;                                     // 32 KB
    float* proj = (float*)(ws + 32768);                           // 8 KB
    unsigned short* Wph = (unsigned short*)(ws + 40960);          // 512 KB
    unsigned short* Wpl = (unsigned short*)(ws + 40960 + 524288); // 512 KB
    float* out  = (float*)d_out;

    zero_kernel<<<dim3(8), dim3(256), 0, stream>>>(esum);
    pack_whh<<<dim3(128), dim3(256), 0, stream>>>(Whh, Wph, Wpl);
    lstm_kernel<<<dim3(N_TRAIN / 16), dim3(512), 0, stream>>>(
        ctx, encW1, encb1, encW2, encb2, Wih, bih, bhh, Wph, Wpl, esum);
    proj_kernel<<<dim3(TSTEPS), dim3(256), 0, stream>>>(esum, attW1, attb1, proj);
    scores_kernel<<<dim3(NANTES / 64), dim3(256), 0, stream>>>(
        S, attW1, proj, attw2, attb2, out);
    argmax_kernel<<<dim3(TSTEPS), dim3(256), 0, stream>>>(out, out);
}

// Round 6
// 843.049 us; speedup vs baseline: 9.5236x; 2.2645x over previous
//
#include <hip/hip_runtime.h>
#include <hip/hip_bf16.h>
#include <math.h>

// Problem constants
#define N_TRAIN 4096
#define N_FEAT  64
#define NHID    256
#define ENC     256
#define GH      256
#define AH      64
#define NANTES  32768
#define TSTEPS  32

#define SSTR 528   // setup LDS row stride (f32)

typedef __attribute__((ext_vector_type(8))) short bf16x8;
typedef __attribute__((ext_vector_type(4))) float f32x4;

__device__ __forceinline__ float sigmoidf_(float x) {
    return 1.0f / (1.0f + __expf(-x));
}
__device__ __forceinline__ float tanhf_(float x) {
    return 1.0f - 2.0f / (__expf(2.0f * x) + 1.0f);
}
__device__ __forceinline__ unsigned short f2bf_rne(float x) {
    unsigned int u = __float_as_uint(x);
    unsigned int r = u + 0x7FFFu + ((u >> 16) & 1u);
    return (unsigned short)(r >> 16);
}
__device__ __forceinline__ float bf2f(unsigned short b) {
    return __uint_as_float(((unsigned int)b) << 16);
}

// ---------------------------------------------------------------------------
// Kernel 0: zero the e-sum accumulator
// ---------------------------------------------------------------------------
__global__ void zero_kernel(float* __restrict__ esum) {
    int tid = blockIdx.x * blockDim.x + threadIdx.x;
    for (int i = tid; i < TSTEPS * GH; i += gridDim.x * blockDim.x)
        esum[i] = 0.0f;
}

// ---------------------------------------------------------------------------
// Kernel P: pack Whh (1024x256 f32) into MFMA-fragment-ordered bf16 (hi only).
// Group g = ((ntile*8 + ks)*64 + lane); 8 elems:
//   Whh[nt*16+(lane&15)][ks*32+(lane>>4)*8 + j]
// -> wave load for (ntile,ks) is one contiguous 1 KB chunk.
// ---------------------------------------------------------------------------
__global__ void pack_whh(const float* __restrict__ Whh,
                         unsigned short* __restrict__ hi)
{
    int g = blockIdx.x * 256 + threadIdx.x;      // 0 .. 32767
    if (g >= 64 * 8 * 64) return;
    int lane  = g & 63;
    int ks    = (g >> 6) & 7;
    int ntile = g >> 9;
    int n  = ntile * 16 + (lane & 15);
    int k0 = ks * 32 + (lane >> 4) * 8;
    const float* src = Whh + n * 256 + k0;
    #pragma unroll
    for (int j = 0; j < 8; ++j)
        hi[g * 8 + j] = f2bf_rne(src[j]);
}

// ---------------------------------------------------------------------------
// Kernel A: fused encoder -> x_proj -> 32-step MFMA LSTM -> per-step h sums
// Grid: 256 blocks x 512 threads (8 waves). Block owns 16 rows (M=16).
// Wave w owns hidden cols [w*32, w*32+32): n-tiles nt(g,u) = 16g + 2w + u,
// processed as two sequential u-halves to keep live VGPRs ~95 (fits the
// 128-reg cap of launch_bounds(512,4) -> 2 blocks/CU, no spills).
// 2-term bf16 split: h = hhi + hlo (bf16 each); Whh as bf16 hi only:
//   gates ~= Ah*Bh + Al*Bh   (B rel err 2^-9; e_t averages 4096 rows).
// ---------------------------------------------------------------------------
__global__ __launch_bounds__(512, 4) void lstm_kernel(
    const float* __restrict__ ctx,
    const float* __restrict__ encW1, const float* __restrict__ encb1,
    const float* __restrict__ encW2, const float* __restrict__ encb2,
    const float* __restrict__ Wih,
    const float* __restrict__ bih,  const float* __restrict__ bhh,
    const unsigned short* __restrict__ Wph,
    float* __restrict__ esum)
{
    __shared__ float sbuf[16 * SSTR];      // 33792 B setup scratch
    __shared__ short hhi[2][16 * 256];     // 16 KB, XOR-swizzled cols
    __shared__ short hlo[2][16 * 256];     // 16 KB

    const int tid   = threadIdx.x;
    const int j     = tid & 255;
    const int rh    = tid >> 8;
    const int rbase = rh * 8;
    const int r0    = blockIdx.x * 16;

    // ==================== setup (f32, one-time) ====================
    // hid = relu(ctx @ encW1 + b1) -> sbuf cols [0,256)
    {
        float acc[8];
        float b = encb1[j];
        #pragma unroll
        for (int r = 0; r < 8; ++r) acc[r] = b;
        for (int k = 0; k < N_FEAT; ++k) {
            float w = encW1[k * NHID + j];
            #pragma unroll
            for (int r = 0; r < 8; ++r)
                acc[r] = fmaf(ctx[(r0 + rbase + r) * N_FEAT + k], w, acc[r]);
        }
        #pragma unroll
        for (int r = 0; r < 8; ++r)
            sbuf[(rbase + r) * SSTR + j] = fmaxf(acc[r], 0.0f);
    }
    __syncthreads();

    // phi = hid @ encW2 + b2 -> sbuf cols [264,520)
    {
        float p[8];
        float b = encb2[j];
        #pragma unroll
        for (int r = 0; r < 8; ++r) p[r] = b;
        for (int k = 0; k < NHID; ++k) {
            float w = encW2[k * ENC + j];
            #pragma unroll
            for (int r = 0; r < 8; ++r)
                p[r] = fmaf(sbuf[(rbase + r) * SSTR + k], w, p[r]);
        }
        __syncthreads();
        #pragma unroll
        for (int r = 0; r < 8; ++r)
            sbuf[(rbase + r) * SSTR + 264 + j] = p[r];
    }
    __syncthreads();

    // xp[g][r] in registers (reads phi)
    float xp[4][8];
    #pragma unroll
    for (int g = 0; g < 4; ++g) {
        int m = g * 256 + j;
        float b = bih[m] + bhh[m];
        #pragma unroll
        for (int r = 0; r < 8; ++r) xp[g][r] = b;
        const float4* wrow = (const float4*)(Wih + m * ENC);
        for (int k4 = 0; k4 < ENC / 4; ++k4) {
            float4 wv = wrow[k4];
            #pragma unroll
            for (int r = 0; r < 8; ++r) {
                const float* ph = &sbuf[(rbase + r) * SSTR + 264 + k4 * 4];
                float v = xp[g][r];
                v = fmaf(ph[0], wv.x, v);
                v = fmaf(ph[1], wv.y, v);
                v = fmaf(ph[2], wv.z, v);
                v = fmaf(ph[3], wv.w, v);
                xp[g][r] = v;
            }
        }
    }
    __syncthreads();   // phi consumed

    // MFMA-phase lane constants
    const int w    = tid >> 6;        // wave 0..7
    const int l    = tid & 63;
    const int col  = l & 15;          // C col / A row
    const int kp   = l >> 4;          // 0..3
    const int arow = col;
    const int asw  = (arow & 7) << 3; // short-unit XOR swizzle

    // transfer xp -> C-fragment layout via sbuf cols [0,256), one gate at a time
    f32x4 xpf[4][2];
    #pragma unroll 1
    for (int g = 0; g < 4; ++g) {
        #pragma unroll
        for (int r = 0; r < 8; ++r)
            sbuf[(rbase + r) * SSTR + j] = xp[g][r];
        __syncthreads();
        #pragma unroll
        for (int u = 0; u < 2; ++u)
            #pragma unroll
            for (int q = 0; q < 4; ++q)
                xpf[g][u][q] = sbuf[(kp * 4 + q) * SSTR + w * 32 + u * 16 + col];
        __syncthreads();
    }

    // zero h buffer 0
    for (int i = tid; i < 16 * 256; i += 512) { hhi[0][i] = 0; hlo[0][i] = 0; }
    __syncthreads();

    // B pointer: fragment (nt, ks) at (((nt*8)+ks)*64 + l)*8 shorts
    const unsigned short* Bh = Wph + (size_t)l * 8;

    // ==================== LSTM loop ====================
    float c[2][4];
    #pragma unroll
    for (int u = 0; u < 2; ++u)
        #pragma unroll
        for (int q = 0; q < 4; ++q) c[u][q] = 0.0f;

    for (int t = 0; t < TSTEPS; ++t) {
        const short* Ahi = hhi[t & 1];
        const short* Alo = hlo[t & 1];
        short* Nhi = hhi[(t + 1) & 1];
        short* Nlo = hlo[(t + 1) & 1];

        float su[2];
        #pragma unroll 1
        for (int u = 0; u < 2; ++u) {
            f32x4 acc[4];
            #pragma unroll
            for (int g = 0; g < 4; ++g) acc[g] = xpf[g][u];

            #pragma unroll 2
            for (int ks = 0; ks < 8; ++ks) {
                bf16x8 bh[4];
                #pragma unroll
                for (int g = 0; g < 4; ++g)
                    bh[g] = *(const bf16x8*)(Bh +
                        (size_t)(((16 * g + 2 * w + u) * 8 + ks) * 64) * 8);
                bf16x8 ah = *(const bf16x8*)&Ahi[arow * 256 +
                                ((ks * 32 + kp * 8) ^ asw)];
                bf16x8 al = *(const bf16x8*)&Alo[arow * 256 +
                                ((ks * 32 + kp * 8) ^ asw)];
                #pragma unroll
                for (int g = 0; g < 4; ++g) {
                    acc[g] = __builtin_amdgcn_mfma_f32_16x16x32_bf16(al, bh[g], acc[g], 0, 0, 0);
                    acc[g] = __builtin_amdgcn_mfma_f32_16x16x32_bf16(ah, bh[g], acc[g], 0, 0, 0);
                }
            }

            // pointwise for this u-half (register resident)
            float s = 0.0f;
            #pragma unroll
            for (int q = 0; q < 4; ++q) {
                float iv = sigmoidf_(acc[0][q]);
                float fv = sigmoidf_(acc[1][q]);
                float gv = tanhf_   (acc[2][q]);
                float ov = sigmoidf_(acc[3][q]);
                c[u][q] = fv * c[u][q] + iv * gv;
                float hv = ov * tanhf_(c[u][q]);
                s += hv;
                unsigned short h16 = f2bf_rne(hv);
                float lof = hv - bf2f(h16);
                int row  = kp * 4 + q;
                int hcol = w * 32 + u * 16 + col;
                int sidx = row * 256 + (hcol ^ ((row & 7) << 3));
                Nhi[sidx] = (short)h16;
                Nlo[sidx] = (short)f2bf_rne(lof);
            }
            su[u] = s;
        }

        // e-sum: reduce over the 16 rows (kp groups share col)
        #pragma unroll
        for (int u = 0; u < 2; ++u) {
            float v = su[u];
            v += __shfl_xor(v, 16);
            v += __shfl_xor(v, 32);
            if (l < 16)
                atomicAdd(&esum[t * GH + w * 32 + u * 16 + l], v);
        }
        __syncthreads();
    }
}

// ---------------------------------------------------------------------------
// Kernel C: proj[t][c] = (esum[t]/4096) @ W1_h + att_b1[c]
// ---------------------------------------------------------------------------
__global__ void proj_kernel(const float* __restrict__ esum,
                            const float* __restrict__ attW1,
                            const float* __restrict__ attb1,
                            float* __restrict__ proj)
{
    __shared__ float part[4][AH];
    const int t   = blockIdx.x;
    const int cix = threadIdx.x & 63;
    const int g   = threadIdx.x >> 6;
    float a = 0.0f;
    #pragma unroll 4
    for (int k = g * 64; k < g * 64 + 64; ++k) {
        float e = esum[t * GH + k] * (1.0f / (float)N_TRAIN);
        a = fmaf(e, attW1[(size_t)(N_TRAIN + k) * AH + cix], a);
    }
    part[g][cix] = a;
    __syncthreads();
    if (threadIdx.x < AH)
        proj[t * AH + cix] = part[0][cix] + part[1][cix] + part[2][cix] +
                             part[3][cix] + attb1[cix];
}

// ---------------------------------------------------------------------------
// Kernel D: S_proj (registers) fused with per-step scores.
// ---------------------------------------------------------------------------
__global__ __launch_bounds__(256, 2) void scores_kernel(
    const float* __restrict__ S,
    const float* __restrict__ attW1,
    const float* __restrict__ proj,
    const float* __restrict__ attw2,
    const float* __restrict__ attb2,
    float* __restrict__ out)
{
    __shared__ float wl[64 * AH];
    __shared__ float projl[TSTEPS * AH];
    __shared__ float w2l[AH];
    __shared__ float part[256];

    const int tid = threadIdx.x;
    const int a0  = blockIdx.x * 64;
    const int ai  = tid & 63;
    const int ch  = tid >> 6;
    const int a   = a0 + ai;

    float sp[16];
    #pragma unroll
    for (int q = 0; q < 16; ++q) sp[q] = 0.0f;

#define LOADS(dst, base_row) do {                                            \
        _Pragma("unroll") for (int i = 0; i < 16; ++i)                       \
            dst[i] = Scol[(size_t)((base_row) + i) * NANTES];                \
    } while (0)

#define COMPS(src, base_row) do {                                            \
        _Pragma("unroll") for (int i = 0; i < 16; ++i) {                     \
            const float* wp = &wl[((base_row) + i) * AH + ch * 16];          \
            float s = src[i];                                                \
            _Pragma("unroll") for (int q = 0; q < 16; ++q)                   \
                sp[q] = fmaf(s, wp[q], sp[q]);                               \
        }                                                                    \
    } while (0)

    for (int chunk = 0; chunk < N_TRAIN / 64; ++chunk) {
        __syncthreads();
        {
            const float4* src = (const float4*)(attW1 + (size_t)chunk * 64 * AH);
            float4* dstv = (float4*)wl;
            for (int i = tid; i < 64 * AH / 4; i += 256) dstv[i] = src[i];
        }
        __syncthreads();

        const float* Scol = S + (size_t)(chunk * 64) * NANTES + a;
        float sA[16], sB[16];
        LOADS(sA, 0);
        LOADS(sB, 16);
        COMPS(sA, 0);
        LOADS(sA, 32);
        COMPS(sB, 16);
        LOADS(sB, 48);
        COMPS(sA, 32);
        COMPS(sB, 48);
    }
#undef LOADS
#undef COMPS

    for (int t = tid; t < TSTEPS * AH; t += 256) projl[t] = proj[t];
    if (tid < AH) w2l[tid] = attw2[tid];
    __syncthreads();

    const float b2v = attb2[0];
    for (int t = 0; t < TSTEPS; ++t) {
        float s = 0.0f;
        const float* pr  = &projl[t * AH + ch * 16];
        const float* w2p = &w2l[ch * 16];
        #pragma unroll
        for (int q = 0; q < 16; ++q)
            s += fmaxf(sp[q] + pr[q], 0.0f) * w2p[q];
        part[tid] = s;
        __syncthreads();
        if (tid < 64)
            out[(size_t)t * NANTES + a0 + tid] =
                part[tid] + part[tid + 64] + part[tid + 128] + part[tid + 192] + b2v;
        __syncthreads();
    }
}

// ---------------------------------------------------------------------------
// Kernel E: per-step argmax (first-max semantics).
// ---------------------------------------------------------------------------
__global__ void argmax_kernel(const float* __restrict__ scores,
                              float* __restrict__ out)
{
    __shared__ float bv[256];
    __shared__ int   bidx[256];
    const int t = blockIdx.x, tid = threadIdx.x;
    float best = -INFINITY;
    int   bi   = 0x7fffffff;
    for (int a = tid; a < NANTES; a += 256) {
        float v = scores[(size_t)t * NANTES + a];
        if (v > best) { best = v; bi = a; }
    }
    bv[tid] = best; bidx[tid] = bi;
    __syncthreads();
    for (int s = 128; s > 0; s >>= 1) {
        if (tid < s) {
            if (bv[tid + s] > bv[tid] ||
                (bv[tid + s] == bv[tid] && bidx[tid + s] < bidx[tid])) {
                bv[tid] = bv[tid + s];
                bidx[tid] = bidx[tid + s];
            }
        }
        __syncthreads();
    }
    if (tid == 0)
        out[(size_t)TSTEPS * NANTES + t] = (float)bidx[0];
}

// ---------------------------------------------------------------------------
extern "C" void kernel_launch(void* const* d_in, const int* in_sizes, int n_in,
                              void* d_out, int out_size, void* d_ws, size_t ws_size,
                              hipStream_t stream)
{
    const float* ctx   = (const float*)d_in[0];
    const float* S     = (const float*)d_in[1];
    const float* encW1 = (const float*)d_in[2];
    const float* encb1 = (const float*)d_in[3];
    const float* encW2 = (const float*)d_in[4];
    const float* encb2 = (const float*)d_in[5];
    const float* Wih   = (const float*)d_in[6];
    const float* Whh   = (const float*)d_in[7];
    const float* bih   = (const float*)d_in[8];
    const float* bhh   = (const float*)d_in[9];
    const float* attW1 = (const float*)d_in[10];
    const float* attb1 = (const float*)d_in[11];
    const float* attw2 = (const float*)d_in[12];
    const float* attb2 = (const float*)d_in[13];

    char* ws = (char*)d_ws;
    float* esum = (float*)ws;                                // 32 KB
    float* proj = (float*)(ws + 32768);                      // 8 KB
    unsigned short* Wph = (unsigned short*)(ws + 40960);     // 512 KB
    float* out  = (float*)d_out;

    zero_kernel<<<dim3(8), dim3(256), 0, stream>>>(esum);
    pack_whh<<<dim3(128), dim3(256), 0, stream>>>(Whh, Wph);
    lstm_kernel<<<dim3(N_TRAIN / 16), dim3(512), 0, stream>>>(
        ctx, encW1, encb1, encW2, encb2, Wih, bih, bhh, Wph, esum);
    proj_kernel<<<dim3(TSTEPS), dim3(256), 0, stream>>>(esum, attW1, attb1, proj);
    scores_kernel<<<dim3(NANTES / 64), dim3(256), 0, stream>>>(
        S, attW1, proj, attw2, attb2, out);
    argmax_kernel<<<dim3(TSTEPS), dim3(256), 0, stream>>>(out, out);
}